// Round 9
// baseline (2384.957 us; speedup 1.0000x reference)
//
#include <hip/hip_runtime.h>
#include <math.h>

// ---------------- problem constants ----------------
#define Bb     8
#define Cc     256
#define HEADS  8
#define WS_    12
#define HD     32
#define LL     144
#define NPIX   9216
#define NPLANE 2048
#define NTOK   73728
#define NWIN   512
#define SCALE_ 0.17677669529663687f
#define BN1N   73728.0f
#define GELC   0.7071067811865476f

// workspace layout (floats)
#define OFF_DT    0           // DCT frag tables: 4 x 9216 shorts = 18432 floats
#define OFF_FNM   18432
#define OFF_E     92160
#define OFF_MASK  165888
#define OFF_P3    239616
#define OFF_ST1   240192
#define OFF_BN2   240200
#define OFF_BUF0  262144      // 18874368 floats: XTH/XTL(bf16) -> PROJ -> XF
#define OFF_BUF1  19136512    // 18874368: QKV(fp32,14155776) + frag tail -> Y1 -> Z
#define OFF_BUF2  38010880    // 18874368: A(fnorm) -> OH/OL(bf16) -> G ; then frF head

#define QKV_TSEC 4718592      // 512*2*144*32 per q/k/v section (2 heads/pass)
// frag tables inside BUF1 tail (floats offsets relative to BUF1)
#define QF_OFF  14155776      // qkvF: 2*196608 shorts = 196608 floats
#define PF_OFF  14352384      // projF: 2*65536 shorts = 65536 floats

typedef short bf16x8 __attribute__((ext_vector_type(8)));
typedef short s16x4  __attribute__((ext_vector_type(4)));
typedef float f32x4  __attribute__((ext_vector_type(4)));

static __device__ __forceinline__ float sigm(float x){ return 1.0f/(1.0f+__expf(-x)); }

static __device__ __forceinline__ void split2(float f, short& h, short& l){
  unsigned u = __float_as_uint(f);
  unsigned hb = u & 0xffff0000u;
  h = (short)(hb>>16);
  float lo = f - __uint_as_float(hb);
  l = (short)(__float_as_uint(lo)>>16);
}

// ---------------- DCT / IDCT matrices in MFMA B-fragment layout ----------------
__global__ void k_mat(short* DFh, short* DFl, short* MFh, short* MFl){
  int t = blockIdx.x*256 + threadIdx.x;     // 0..18431
  int m = t/9216, u = t - m*9216;
  int k = u/96, n = u - k*96;
  double v;
  if (m == 0){
    v = 2.0*cos(3.14159265358979323846*(double)n*(double)(2*k+1)/192.0);
  } else {
    v = (k==0) ? 1.0 : 2.0*cos(3.14159265358979323846*(double)k*(double)(2*n+1)/192.0);
    if (k == 94) v += cos(3.14159265358979323846*94.0/192.0) * ((n&1)? -1.0 : 1.0);
    v /= 192.0;
  }
  float f = (float)v;
  short hs, ls; split2(f, hs, ls);
  int kt = k>>5, lr = (k>>3)&3, jj = k&7, nt = n>>4;
  int idx = ((kt*6+nt)*64 + (lr*16 + (n&15)))*8 + jj;
  if (m == 0){ DFh[idx]=hs; DFl[idx]=ls; }
  else       { MFh[idx]=hs; MFl[idx]=ls; }
}

// ---------------- weight fragment packing ----------------
__global__ void k_wfrag(const float* __restrict__ qw, const float* __restrict__ pw,
                        short* QFh, short* QFl, short* PFh, short* PFl){
  int t = blockIdx.x*256 + threadIdx.x;   // 0..262143
  if (t < 196608){
    int wrow = t>>8, k = t&255;
    int sec = wrow>>8, rem = wrow&255, head = rem>>5, d = rem&31;
    int g = head>>1, hl = head&1;
    int nl = sec*64 + hl*32 + d;
    int idx = (((g*8 + (k>>5))*12 + (nl>>4))*64 + ((k>>3)&3)*16 + (nl&15))*8 + (k&7);
    short h,l; split2(qw[t],h,l); QFh[idx]=h; QFl[idx]=l;
  } else {
    int u = t - 196608;
    int n = u>>8, k = u&255;
    int idx = (((k>>5)*16 + (n>>4))*64 + ((k>>3)&3)*16 + (n&15))*8 + (k&7);
    short h,l; split2(pw[u],h,l); PFh[idx]=h; PFl[idx]=l;
  }
}

__global__ void k_wfrag_fr(const float* __restrict__ fw, short* FFh, short* FFl){
  int u = blockIdx.x*256 + threadIdx.x;   // 0..65535
  int n = u>>8, k = u&255;
  int idx = (((k>>5)*16 + (n>>4))*64 + ((k>>3)&3)*16 + (n&15))*8 + (k&7);
  short h,l; split2(fw[u],h,l); FFh[idx]=h; FFl[idx]=l;
}

// ---------------- batched plane transform  Y = F^T X F  via MFMA (split-bf16) ----------------
__global__ __launch_bounds__(256) void k_plane(const float* __restrict__ in, float* __restrict__ out,
                                               const short* __restrict__ Fh, const short* __restrict__ Fl,
                                               int mode){
  __shared__ __align__(16) short Xh[96*104];
  __shared__ __align__(16) short Xl[96*104];
  __shared__ float red[512];
  const int tid = threadIdx.x;
  const int lane = tid & 63, wid = tid >> 6;
  const int l15 = lane & 15, l4 = lane >> 4;
  const float* src = in + (size_t)blockIdx.x*NPIX;

  for (int t4 = tid; t4 < 576; t4 += 256){
    int rt = t4/24, ct = t4 - rt*24;
    const float* p0 = src + rt*4*96 + ct*4;
    float4 v0 = *(const float4*)(p0);
    float4 v1 = *(const float4*)(p0+96);
    float4 v2 = *(const float4*)(p0+192);
    float4 v3 = *(const float4*)(p0+288);
#define STCOL(f0,f1,f2,f3,j) { s16x4 hv, lv; short hs, ls; \
    split2(f0,hs,ls); hv[0]=hs; lv[0]=ls; \
    split2(f1,hs,ls); hv[1]=hs; lv[1]=ls; \
    split2(f2,hs,ls); hv[2]=hs; lv[2]=ls; \
    split2(f3,hs,ls); hv[3]=hs; lv[3]=ls; \
    int cc = ct*4+(j); \
    *(s16x4*)&Xh[cc*104 + rt*4] = hv; \
    *(s16x4*)&Xl[cc*104 + rt*4] = lv; }
    STCOL(v0.x,v1.x,v2.x,v3.x,0)
    STCOL(v0.y,v1.y,v2.y,v3.y,1)
    STCOL(v0.z,v1.z,v2.z,v3.z,2)
    STCOL(v0.w,v1.w,v2.w,v3.w,3)
#undef STCOL
  }
  __syncthreads();

  f32x4 acc[9];
  #pragma unroll
  for (int t=0;t<9;++t) acc[t] = (f32x4){0.f,0.f,0.f,0.f};

  #pragma unroll
  for (int t=0;t<9;++t){
    int gt = wid*9 + t;
    int mt = gt/6, nt = gt - mt*6;
    int arow = mt*16 + l15;
    #pragma unroll
    for (int kb=0;kb<3;++kb){
      bf16x8 ah = *(const bf16x8*)&Xh[arow*104 + kb*32 + l4*8];
      bf16x8 al = *(const bf16x8*)&Xl[arow*104 + kb*32 + l4*8];
      const bf16x8 bh = *(const bf16x8*)(Fh + (size_t)((kb*6+nt)*64 + lane)*8);
      const bf16x8 bl = *(const bf16x8*)(Fl + (size_t)((kb*6+nt)*64 + lane)*8);
      acc[t] = __builtin_amdgcn_mfma_f32_16x16x32_bf16(al, bh, acc[t], 0,0,0);
      acc[t] = __builtin_amdgcn_mfma_f32_16x16x32_bf16(ah, bl, acc[t], 0,0,0);
      acc[t] = __builtin_amdgcn_mfma_f32_16x16x32_bf16(ah, bh, acc[t], 0,0,0);
    }
  }
  __syncthreads();

  #pragma unroll
  for (int t=0;t<9;++t){
    int gt = wid*9 + t;
    int mt = gt/6, nt = gt - mt*6;
    int ti = nt*16 + l15, tj = mt*16 + l4*4;
    s16x4 hv, lv; short hs, ls;
    split2(acc[t][0],hs,ls); hv[0]=hs; lv[0]=ls;
    split2(acc[t][1],hs,ls); hv[1]=hs; lv[1]=ls;
    split2(acc[t][2],hs,ls); hv[2]=hs; lv[2]=ls;
    split2(acc[t][3],hs,ls); hv[3]=hs; lv[3]=ls;
    *(s16x4*)&Xh[ti*104+tj] = hv;
    *(s16x4*)&Xl[ti*104+tj] = lv;
  }
  #pragma unroll
  for (int t=0;t<9;++t) acc[t] = (f32x4){0.f,0.f,0.f,0.f};
  __syncthreads();

  #pragma unroll
  for (int t=0;t<9;++t){
    int gt = wid*9 + t;
    int it = gt/6, jt = gt - it*6;
    int arow = it*16 + l15;
    #pragma unroll
    for (int kb=0;kb<3;++kb){
      bf16x8 ah = *(const bf16x8*)&Xh[arow*104 + kb*32 + l4*8];
      bf16x8 al = *(const bf16x8*)&Xl[arow*104 + kb*32 + l4*8];
      const bf16x8 bh = *(const bf16x8*)(Fh + (size_t)((kb*6+jt)*64 + lane)*8);
      const bf16x8 bl = *(const bf16x8*)(Fl + (size_t)((kb*6+jt)*64 + lane)*8);
      acc[t] = __builtin_amdgcn_mfma_f32_16x16x32_bf16(al, bh, acc[t], 0,0,0);
      acc[t] = __builtin_amdgcn_mfma_f32_16x16x32_bf16(ah, bl, acc[t], 0,0,0);
      acc[t] = __builtin_amdgcn_mfma_f32_16x16x32_bf16(ah, bh, acc[t], 0,0,0);
    }
  }

  float* dst = out + (size_t)blockIdx.x*NPIX;
  if (mode == 2){
    #pragma unroll
    for (int t=0;t<9;++t){
      int gt = wid*9 + t;
      int it = gt/6, jt = gt - it*6;
      int i0 = it*16 + l4*4, j = jt*16 + l15;
      dst[(i0+0)*96 + j] = acc[t][0];
      dst[(i0+1)*96 + j] = acc[t][1];
      dst[(i0+2)*96 + j] = acc[t][2];
      dst[(i0+3)*96 + j] = acc[t][3];
    }
  } else if (mode == 0){
    float lmn = 3.4e38f, lmx = 0.f;
    #pragma unroll
    for (int t=0;t<9;++t){
      #pragma unroll
      for (int p=0;p<4;++p){ float a = fabsf(acc[t][p]); lmn = fminf(lmn,a); lmx = fmaxf(lmx,a); }
    }
    red[tid]=lmn; red[256+tid]=lmx; __syncthreads();
    for (int o=128;o;o>>=1){
      if (tid<o){ red[tid]=fminf(red[tid],red[tid+o]); red[256+tid]=fmaxf(red[256+tid],red[256+tid+o]); }
      __syncthreads();
    }
    float mn = red[0], inv = 1.f/(red[256]+1e-6f);
    #pragma unroll
    for (int t=0;t<9;++t){
      int gt = wid*9 + t;
      int it = gt/6, jt = gt - it*6;
      int i0 = it*16 + l4*4, j = jt*16 + l15;
      dst[(i0+0)*96 + j] = (fabsf(acc[t][0])-mn)*inv;
      dst[(i0+1)*96 + j] = (fabsf(acc[t][1])-mn)*inv;
      dst[(i0+2)*96 + j] = (fabsf(acc[t][2])-mn)*inv;
      dst[(i0+3)*96 + j] = (fabsf(acc[t][3])-mn)*inv;
    }
  } else {
    float ls = 0.f;
    #pragma unroll
    for (int t=0;t<9;++t){
      #pragma unroll
      for (int p=0;p<4;++p) ls += acc[t][p];
    }
    red[tid]=ls; __syncthreads();
    for (int o=128;o;o>>=1){ if (tid<o) red[tid]+=red[tid+o]; __syncthreads(); }
    float mean = red[0]*(1.f/9216.f);
    #pragma unroll
    for (int t=0;t<9;++t){
      int gt = wid*9 + t;
      int it = gt/6, jt = gt - it*6;
      int i0 = it*16 + l4*4, j = jt*16 + l15;
      #pragma unroll
      for (int p=0;p<4;++p){
        float v = acc[t][p];
        dst[(i0+p)*96 + j] = v * sigm(5.f*(fabsf(v)-mean));
      }
    }
  }
}

// ---------------- channel mean ----------------
__global__ void k_chmean(const float* __restrict__ A, float* __restrict__ FNM){
  int px = blockIdx.x*256 + threadIdx.x;
  int b = px/NPIX, p = px - b*NPIX;
  const float* base = A + (size_t)b*Cc*NPIX + p;
  float s = 0.f;
  #pragma unroll 8
  for (int c=0;c<Cc;++c) s += base[(size_t)c*NPIX];
  FNM[px] = s*(1.f/256.f);
}

// ---------------- 3x3 conv (1ch) + partial BN1 stats ----------------
__global__ void k_conv3(const float* __restrict__ FNM, const float* __restrict__ w9,
                        float* __restrict__ E, float* __restrict__ P3){
  __shared__ float rs[256], rq[256];
  int px = blockIdx.x*256 + threadIdx.x;
  int b = px/NPIX, p = px - b*NPIX;
  int h = p/96, w = p - h*96;
  const float* base = FNM + b*NPIX;
  float a = 0.f;
  #pragma unroll
  for (int dy=0;dy<3;++dy){
    int hh = h+dy-1;
    if (hh>=0 && hh<96){
      #pragma unroll
      for (int dx=0;dx<3;++dx){
        int ww2 = w+dx-1;
        if (ww2>=0 && ww2<96) a = fmaf(base[hh*96+ww2], w9[dy*3+dx], a);
      }
    }
  }
  E[px] = a;
  rs[threadIdx.x]=a; rq[threadIdx.x]=a*a; __syncthreads();
  for (int o=128;o;o>>=1){
    if (threadIdx.x<o){ rs[threadIdx.x]+=rs[threadIdx.x+o]; rq[threadIdx.x]+=rq[threadIdx.x+o]; }
    __syncthreads();
  }
  if (threadIdx.x==0){ P3[2*blockIdx.x]=rs[0]; P3[2*blockIdx.x+1]=rq[0]; }
}

__global__ void k_red576(const float* __restrict__ P3, float* __restrict__ ST1){
  __shared__ float rs[256], rq[256];
  float s=0.f,q=0.f;
  for (int i=threadIdx.x;i<288;i+=256){ s+=P3[2*i]; q+=P3[2*i+1]; }
  rs[threadIdx.x]=s; rq[threadIdx.x]=q; __syncthreads();
  for (int o=128;o;o>>=1){
    if (threadIdx.x<o){ rs[threadIdx.x]+=rs[threadIdx.x+o]; rq[threadIdx.x]+=rq[threadIdx.x+o]; }
    __syncthreads();
  }
  if (threadIdx.x==0){ ST1[0]=rs[0]; ST1[1]=rq[0]; }
}

// ---------------- mask ----------------
__global__ void k_mask(const float* __restrict__ E, const float* __restrict__ ST1,
                       const float* __restrict__ g1, const float* __restrict__ b1,
                       const float* __restrict__ nw, const float* __restrict__ nb,
                       float* __restrict__ MASK){
  __shared__ float les[NPIX];
  __shared__ float red[256];
  int b = blockIdx.x, tid = threadIdx.x;
  float m = ST1[0]*(1.f/BN1N);
  float v = ST1[1]*(1.f/BN1N) - m*m;
  float rstd = rsqrtf(v + 1e-5f);
  float ga = g1[0], be = b1[0];
  float local = 0.f;
  for (int p=tid;p<NPIX;p+=256){
    float le = fmaxf(0.f, (E[b*NPIX+p]-m)*rstd*ga + be);
    les[p] = le; local += le;
  }
  red[tid]=local; __syncthreads();
  for (int o=128;o;o>>=1){ if (tid<o) red[tid]+=red[tid+o]; __syncthreads(); }
  float ng = sigm(red[0]*(1.f/9216.f)*nw[0] + nb[0]);
  for (int p=tid;p<NPIX;p+=256)
    MASK[b*NPIX+p] = sigm(1.f - les[p]) * ng;
}

// ---------------- NCHW -> token-major bf16 hi/lo ----------------
__global__ void k_tr(const float* __restrict__ x, short* __restrict__ XTH, short* __restrict__ XTL){
  __shared__ float tile[32][33];
  int pt = blockIdx.x*32, ct = blockIdx.y*32, b = blockIdx.z;
  int txd = threadIdx.x, tyd = threadIdx.y;
  #pragma unroll
  for (int q=0;q<4;++q){
    int c = ct + tyd + q*8;
    tile[tyd+q*8][txd] = x[(size_t)(b*Cc+c)*NPIX + pt + txd];
  }
  __syncthreads();
  #pragma unroll
  for (int q=0;q<4;++q){
    int p = pt + tyd + q*8;
    int h = p/96, w = p - h*96;
    int wh = h/12, lh = h - wh*12, wwi = w/12, lw = w - wwi*12;
    int token = (b*64 + wh*8 + wwi)*144 + lh*12 + lw;
    float v = tile[txd][tyd+q*8];
    short hs, ls; split2(v, hs, ls);
    XTH[(size_t)token*256 + ct + txd] = hs;
    XTL[(size_t)token*256 + ct + txd] = ls;
  }
}

// ---------------- qkv GEMM via MFMA (pass g: heads 2g,2g+1; N=192) ----------------
__global__ __launch_bounds__(256) void k_qkvm(const short* __restrict__ XTH, const short* __restrict__ XTL,
                                              const short* __restrict__ QFh, const short* __restrict__ QFl,
                                              const float* __restrict__ bq, float* __restrict__ qkv, int g){
  const int tid = threadIdx.x, lane = tid&63, wid = tid>>6;
  const int l15 = lane&15, l4 = lane>>4;
  const int M0 = blockIdx.x*128;
  f32x4 acc[2][12];
  #pragma unroll
  for (int m=0;m<2;++m){
    #pragma unroll
    for (int n=0;n<12;++n) acc[m][n] = (f32x4){0.f,0.f,0.f,0.f};
  }
  for (int kb=0; kb<8; ++kb){
    bf16x8 ah[2], al[2];
    #pragma unroll
    for (int m=0;m<2;++m){
      size_t off = (size_t)(M0 + (2*wid+m)*16 + l15)*256 + kb*32 + l4*8;
      ah[m] = *(const bf16x8*)(XTH + off);
      al[m] = *(const bf16x8*)(XTL + off);
    }
    #pragma unroll
    for (int nt=0; nt<12; ++nt){
      const bf16x8 bh = *(const bf16x8*)(QFh + (size_t)(((g*8+kb)*12+nt)*64 + lane)*8);
      const bf16x8 bl = *(const bf16x8*)(QFl + (size_t)(((g*8+kb)*12+nt)*64 + lane)*8);
      #pragma unroll
      for (int m=0;m<2;++m){
        acc[m][nt] = __builtin_amdgcn_mfma_f32_16x16x32_bf16(al[m], bh, acc[m][nt], 0,0,0);
        acc[m][nt] = __builtin_amdgcn_mfma_f32_16x16x32_bf16(ah[m], bl, acc[m][nt], 0,0,0);
        acc[m][nt] = __builtin_amdgcn_mfma_f32_16x16x32_bf16(ah[m], bh, acc[m][nt], 0,0,0);
      }
    }
  }
  #pragma unroll
  for (int m=0;m<2;++m){
    int tok0 = M0 + (2*wid+m)*16 + l4*4;
    int win[4], ll[4];
    #pragma unroll
    for (int p=0;p<4;++p){ int tk = tok0+p; win[p] = tk/144; ll[p] = tk - win[p]*144; }
    #pragma unroll
    for (int nt=0; nt<12; ++nt){
      int n = nt*16 + l15;
      int sec = n>>6, hl = (n>>5)&1, d = n&31;
      float bias = bq[sec*256 + (g*2+hl)*32 + d];
      #pragma unroll
      for (int p=0;p<4;++p){
        qkv[(size_t)sec*QKV_TSEC + ((size_t)(win[p]*2+hl)*144 + ll[p])*32 + d] = acc[m][nt][p] + bias;
      }
    }
  }
}

// ---------------- window attention -> OH/OL bf16 hi/lo token-major ----------------
__global__ __launch_bounds__(192) void k_attn(const float* __restrict__ qkv, const float* __restrict__ rpb,
                                              short* __restrict__ OH, short* __restrict__ OL, int g){
  __shared__ __align__(16) float qt[32*144];
  __shared__ __align__(16) float Ks[144*32];
  __shared__ __align__(16) float Vs[144*32];
  __shared__ float rpbs[532];
  const int win = blockIdx.x, hl = blockIdx.y;
  const int head = g*2 + hl;
  const int tid = threadIdx.x;
  const float* Qg = qkv + ((size_t)(win*2+hl)*144)*32;
  const float* Kg = Qg + QKV_TSEC;
  const float* Vg = Qg + 2*(size_t)QKV_TSEC;
  for (int t=tid; t<4608; t+=192){
    Ks[t] = Kg[t]; Vs[t] = Vg[t];
    int l = t>>5, d = t&31;
    qt[d*144+l] = Qg[t];
  }
  for (int t=tid; t<529; t+=192) rpbs[t] = rpb[t*8 + head];
  __syncthreads();

  int r = tid;
  if (r < 144){
    float q[32];
    #pragma unroll
    for (int d=0;d<32;++d) q[d] = qt[d*144+r];
    float o[32];
    #pragma unroll
    for (int d=0;d<32;++d) o[d]=0.f;
    float m = -3.4e38f, sum = 0.f;
    int rh = r/12, rw = r - rh*12;
    int jh = 0, jw = 0;
    for (int j=0;j<144;++j){
      const float4* kp = (const float4*)&Ks[j*32];
      float s0=0,s1=0,s2=0,s3=0;
      #pragma unroll
      for (int t=0;t<8;++t){
        float4 kv = kp[t];
        s0 = fmaf(q[4*t+0],kv.x,s0); s1 = fmaf(q[4*t+1],kv.y,s1);
        s2 = fmaf(q[4*t+2],kv.z,s2); s3 = fmaf(q[4*t+3],kv.w,s3);
      }
      float s = ((s0+s1)+(s2+s3))*SCALE_ + rpbs[(rh-jh+11)*23 + (rw-jw+11)];
      float mn2 = fmaxf(m, s);
      if (mn2 > m){
        float corr = __expf(m - mn2);
        sum *= corr;
        #pragma unroll
        for (int d=0;d<32;++d) o[d]*=corr;
        m = mn2;
      }
      float p = __expf(s - m);
      sum += p;
      const float4* vp = (const float4*)&Vs[j*32];
      #pragma unroll
      for (int t=0;t<8;++t){
        float4 vv = vp[t];
        o[4*t+0]=fmaf(p,vv.x,o[4*t+0]); o[4*t+1]=fmaf(p,vv.y,o[4*t+1]);
        o[4*t+2]=fmaf(p,vv.z,o[4*t+2]); o[4*t+3]=fmaf(p,vv.w,o[4*t+3]);
      }
      if (++jw==12){ jw=0; ++jh; }
    }
    float inv = 1.f/sum;
    size_t base = ((size_t)(win*144+r))*256 + head*32;
    #pragma unroll
    for (int t=0;t<8;++t){
      s16x4 hv, lv; short hs, ls;
      split2(o[4*t+0]*inv,hs,ls); hv[0]=hs; lv[0]=ls;
      split2(o[4*t+1]*inv,hs,ls); hv[1]=hs; lv[1]=ls;
      split2(o[4*t+2]*inv,hs,ls); hv[2]=hs; lv[2]=ls;
      split2(o[4*t+3]*inv,hs,ls); hv[3]=hs; lv[3]=ls;
      *(s16x4*)&OH[base + 4*t] = hv;
      *(s16x4*)&OL[base + 4*t] = lv;
    }
  }
}

// ---------------- proj GEMM via MFMA -> PROJ token-major fp32 ----------------
__global__ __launch_bounds__(256) void k_projm(const short* __restrict__ OH, const short* __restrict__ OL,
                                               const short* __restrict__ PFh, const short* __restrict__ PFl,
                                               const float* __restrict__ bp, float* __restrict__ PROJ){
  const int tid = threadIdx.x, lane = tid&63, wid = tid>>6;
  const int l15 = lane&15, l4 = lane>>4;
  const int M0 = blockIdx.x*128;
  const int N0 = blockIdx.y*128;
  f32x4 acc[2][8];
  #pragma unroll
  for (int m=0;m<2;++m){
    #pragma unroll
    for (int n=0;n<8;++n) acc[m][n] = (f32x4){0.f,0.f,0.f,0.f};
  }
  for (int kb=0; kb<8; ++kb){
    bf16x8 ah[2], al[2];
    #pragma unroll
    for (int m=0;m<2;++m){
      size_t off = (size_t)(M0 + (2*wid+m)*16 + l15)*256 + kb*32 + l4*8;
      ah[m] = *(const bf16x8*)(OH + off);
      al[m] = *(const bf16x8*)(OL + off);
    }
    #pragma unroll
    for (int nt=0; nt<8; ++nt){
      int ntg = (N0>>4) + nt;
      const bf16x8 bh = *(const bf16x8*)(PFh + (size_t)((kb*16+ntg)*64 + lane)*8);
      const bf16x8 bl = *(const bf16x8*)(PFl + (size_t)((kb*16+ntg)*64 + lane)*8);
      #pragma unroll
      for (int m=0;m<2;++m){
        acc[m][nt] = __builtin_amdgcn_mfma_f32_16x16x32_bf16(al[m], bh, acc[m][nt], 0,0,0);
        acc[m][nt] = __builtin_amdgcn_mfma_f32_16x16x32_bf16(ah[m], bl, acc[m][nt], 0,0,0);
        acc[m][nt] = __builtin_amdgcn_mfma_f32_16x16x32_bf16(ah[m], bh, acc[m][nt], 0,0,0);
      }
    }
  }
  #pragma unroll
  for (int m=0;m<2;++m){
    int tok0 = M0 + (2*wid+m)*16 + l4*4;
    #pragma unroll
    for (int nt=0; nt<8; ++nt){
      int n = N0 + nt*16 + l15;
      float bias = bp[n];
      #pragma unroll
      for (int p=0;p<4;++p){
        PROJ[(size_t)(tok0+p)*256 + n] = acc[m][nt][p] + bias;
      }
    }
  }
}

// ---------------- merge: Y1 = transpose(PROJ) + LPE*mask ----------------
__global__ __launch_bounds__(256) void k_merge(const float* __restrict__ PROJ, const float* __restrict__ x,
                                               const float* __restrict__ lpw, const float* __restrict__ lpb,
                                               const float* __restrict__ lps, const float* __restrict__ MASK,
                                               float* __restrict__ Y1){
  __shared__ float T[96*65];
  const int bx = blockIdx.x;          // b*96 + h
  const int b = bx/96, h = bx - b*96;
  const int wh = h/12, lh = h - wh*12;
  const int c0 = blockIdx.y*64;
  const int t = threadIdx.x;
  const int wave = t>>6, lane = t&63;
  for (int it=0; it<24; ++it){
    int tok = wave*24 + it;
    int wwi = tok/12, lw2 = tok - wwi*12;
    int gtok = (b*64 + wh*8 + wwi)*144 + lh*12 + lw2;
    T[tok*65 + lane] = PROJ[(size_t)gtok*256 + c0 + lane];
  }
  __syncthreads();
  const int cl = t>>2, q = t&3, p0 = q*24;
  const int c = c0 + cl;
  const float* xc = x + (size_t)(b*Cc + c)*NPIX;
  const float* wp = lpw + c*9;
  float w0=wp[0],w1=wp[1],w2=wp[2],w3=wp[3],w4=wp[4],w5=wp[5],w6=wp[6],w7=wp[7],w8=wp[8];
  float bias = lpb[c], scale = lps[0];
  const float* mrow = MASK + b*NPIX + h*96;
  const float* r0 = xc + (h-1)*96;
  const float* r1 = xc + h*96;
  const float* r2 = xc + (h+1)*96;
  bool h0 = (h>0), h2 = (h<95);
  float outv[24];
  #pragma unroll 4
  for (int i=0;i<24;++i){
    int w = p0 + i;
    bool wl = (w>0), wr = (w<95);
    float a = 0.f;
    if (h0){
      if (wl) a = fmaf(r0[w-1],w0,a);
      a = fmaf(r0[w],w1,a);
      if (wr) a = fmaf(r0[w+1],w2,a);
    }
    if (wl) a = fmaf(r1[w-1],w3,a);
    a = fmaf(r1[w],w4,a);
    if (wr) a = fmaf(r1[w+1],w5,a);
    if (h2){
      if (wl) a = fmaf(r2[w-1],w6,a);
      a = fmaf(r2[w],w7,a);
      if (wr) a = fmaf(r2[w+1],w8,a);
    }
    outv[i] = (a + bias)*scale*mrow[w];
  }
  float* dst = Y1 + (size_t)(b*Cc + c)*NPIX + h*96 + p0;
  #pragma unroll
  for (int i=0;i<24;i+=4){
    float4 v = { T[(p0+i)*65+cl]+outv[i], T[(p0+i+1)*65+cl]+outv[i+1],
                 T[(p0+i+2)*65+cl]+outv[i+2], T[(p0+i+3)*65+cl]+outv[i+3] };
    *(float4*)&dst[i] = v;
  }
}

// ---------------- 1x1 refine conv via MFMA: Z = fr_w @ (x + XF) ----------------
__global__ __launch_bounds__(256) void k_conv1x1m(const float* __restrict__ x, const float* __restrict__ XF,
                                                  const short* __restrict__ FFh, const short* __restrict__ FFl,
                                                  float* __restrict__ Z){
  __shared__ __align__(16) short Ah[64*40];
  __shared__ __align__(16) short Al[64*40];
  const int tid = threadIdx.x, lane = tid&63, wid = tid>>6;
  const int l15 = lane&15, l4 = lane>>4;
  const int g0 = blockIdx.x*64;
  const int b = g0/NPIX, p0 = g0 - b*NPIX;
  f32x4 acc[16];
  #pragma unroll
  for (int n=0;n<16;++n) acc[n] = (f32x4){0.f,0.f,0.f,0.f};

  for (int kb=0; kb<8; ++kb){
    if (kb) __syncthreads();
    if (tid < 128){
      int cq = tid>>4, pq = tid&15;    // 8 channel-quads x 16 pixel-quads
      float vv[4][4];
      #pragma unroll
      for (int j=0;j<4;++j){
        size_t off = (size_t)(b*Cc + kb*32 + cq*4 + j)*NPIX + p0 + pq*4;
        float4 va = *(const float4*)&x[off];
        float4 vb = *(const float4*)&XF[off];
        vv[j][0]=va.x+vb.x; vv[j][1]=va.y+vb.y; vv[j][2]=va.z+vb.z; vv[j][3]=va.w+vb.w;
      }
      #pragma unroll
      for (int j2=0;j2<4;++j2){
        s16x4 hv, lv; short hs, ls;
        split2(vv[0][j2],hs,ls); hv[0]=hs; lv[0]=ls;
        split2(vv[1][j2],hs,ls); hv[1]=hs; lv[1]=ls;
        split2(vv[2][j2],hs,ls); hv[2]=hs; lv[2]=ls;
        split2(vv[3][j2],hs,ls); hv[3]=hs; lv[3]=ls;
        *(s16x4*)&Ah[(pq*4+j2)*40 + cq*4] = hv;
        *(s16x4*)&Al[(pq*4+j2)*40 + cq*4] = lv;
      }
    }
    __syncthreads();
    bf16x8 ah = *(const bf16x8*)&Ah[(wid*16+l15)*40 + l4*8];
    bf16x8 al = *(const bf16x8*)&Al[(wid*16+l15)*40 + l4*8];
    #pragma unroll
    for (int nt=0; nt<16; ++nt){
      const bf16x8 bh = *(const bf16x8*)(FFh + (size_t)((kb*16+nt)*64 + lane)*8);
      const bf16x8 bl = *(const bf16x8*)(FFl + (size_t)((kb*16+nt)*64 + lane)*8);
      acc[nt] = __builtin_amdgcn_mfma_f32_16x16x32_bf16(al, bh, acc[nt], 0,0,0);
      acc[nt] = __builtin_amdgcn_mfma_f32_16x16x32_bf16(ah, bl, acc[nt], 0,0,0);
      acc[nt] = __builtin_amdgcn_mfma_f32_16x16x32_bf16(ah, bh, acc[nt], 0,0,0);
    }
  }
  #pragma unroll
  for (int nt=0; nt<16; ++nt){
    int cch = nt*16 + l15;
    float* zp = Z + (size_t)(b*Cc + cch)*NPIX + p0 + wid*16 + l4*4;
    *(f32x4*)zp = acc[nt];
  }
}

// ---------------- BN2 stats ----------------
__global__ void k_bnstat(const float* __restrict__ Z, float* __restrict__ BN2){
  __shared__ float rs[256], rq[256];
  int c = blockIdx.x, tid = threadIdx.x;
  float s=0.f,q=0.f;
  for (int b=0;b<Bb;++b){
    const float* pl = Z + ((size_t)(b*Cc+c))*NPIX;
    for (int i=tid;i<NPIX/4;i+=256){
      float4 v = *(const float4*)&pl[i*4];
      s += v.x+v.y+v.z+v.w;
      q += v.x*v.x + v.y*v.y + v.z*v.z + v.w*v.w;
    }
  }
  rs[tid]=s; rq[tid]=q; __syncthreads();
  for (int o=128;o;o>>=1){
    if (tid<o){ rs[tid]+=rs[tid+o]; rq[tid]+=rq[tid+o]; }
    __syncthreads();
  }
  if (tid==0){ BN2[c]=rs[0]; BN2[256+c]=rq[0]; }
}

// ---------------- final: BN2 + exact GELU ----------------
__global__ void k_final(const float* __restrict__ Z, const float* __restrict__ BN2,
                        const float* __restrict__ g2, const float* __restrict__ b2,
                        float* __restrict__ out){
  size_t f4 = (size_t)blockIdx.x*256 + threadIdx.x;
  size_t base = f4*4;
  int c = (int)((base/NPIX) & 255);
  float m = BN2[c]*(1.f/BN1N);
  float v = BN2[256+c]*(1.f/BN1N) - m*m;
  float rstd = rsqrtf(v+1e-5f);
  float ga = g2[c], be = b2[c];
  float4 z = *(const float4*)&Z[base];
  float4 r;
  float y;
  y = (z.x-m)*rstd*ga + be; r.x = 0.5f*y*(1.f+erff(y*GELC));
  y = (z.y-m)*rstd*ga + be; r.y = 0.5f*y*(1.f+erff(y*GELC));
  y = (z.z-m)*rstd*ga + be; r.z = 0.5f*y*(1.f+erff(y*GELC));
  y = (z.w-m)*rstd*ga + be; r.w = 0.5f*y*(1.f+erff(y*GELC));
  *(float4*)&out[base] = r;
}

// ---------------- launch ----------------
extern "C" void kernel_launch(void* const* d_in, const int* in_sizes, int n_in,
                              void* d_out, int out_size, void* d_ws, size_t ws_size,
                              hipStream_t stream){
  const float* x      = (const float*)d_in[0];
  const float* qkv_w  = (const float*)d_in[1];
  const float* qkv_b  = (const float*)d_in[2];
  const float* proj_w = (const float*)d_in[3];
  const float* proj_b = (const float*)d_in[4];
  const float* lpe_w  = (const float*)d_in[5];
  const float* lpe_b  = (const float*)d_in[6];
  const float* lpe_s  = (const float*)d_in[7];
  const float* rpb    = (const float*)d_in[8];
  const float* ec_w   = (const float*)d_in[9];
  const float* bn1_g  = (const float*)d_in[10];
  const float* bn1_b  = (const float*)d_in[11];
  const float* nl_w   = (const float*)d_in[12];
  const float* nl_b   = (const float*)d_in[13];
  const float* fr_w   = (const float*)d_in[14];
  const float* bn2_g  = (const float*)d_in[15];
  const float* bn2_b  = (const float*)d_in[16];
  float* outp = (float*)d_out;

  float* WS   = (float*)d_ws;
  short* DFh  = (short*)(WS + OFF_DT);
  short* DFl  = DFh + 9216;
  short* MFh  = DFh + 18432;
  short* MFl  = DFh + 27648;
  float* FNM  = WS + OFF_FNM;
  float* E    = WS + OFF_E;
  float* MASK = WS + OFF_MASK;
  float* P3   = WS + OFF_P3;
  float* ST1  = WS + OFF_ST1;
  float* BN2  = WS + OFF_BN2;
  float* BUF0 = WS + OFF_BUF0;
  float* BUF1 = WS + OFF_BUF1;
  float* BUF2 = WS + OFF_BUF2;

  short* XTH = (short*)BUF0;                 // 18874368 shorts
  short* XTL = XTH + 18874368;
  float* PROJ = BUF0;                        // after qkv passes
  float* XF   = BUF0;                        // after idct

  float* QKV = BUF1;                         // 14155776 floats
  short* QFh = (short*)(BUF1 + QF_OFF);      // 196608 shorts
  short* QFl = QFh + 196608;
  short* PFh = (short*)(BUF1 + PF_OFF);      // 65536 shorts
  short* PFl = PFh + 65536;
  float* Y1  = BUF1;
  float* Zb  = BUF1;

  float* A2  = BUF2;                         // freqnorm
  short* OH  = (short*)BUF2;                 // attn out bf16 hi
  short* OL  = OH + 18874368;
  float* G   = BUF2;                         // gate output
  short* FFh = (short*)BUF2;                 // fr_w frags (written after idct)
  short* FFl = FFh + 65536;

  k_mat<<<72,256,0,stream>>>(DFh, DFl, MFh, MFl);
  k_wfrag<<<1024,256,0,stream>>>(qkv_w, proj_w, QFh, QFl, PFh, PFl);
  // freq detector
  k_plane<<<NPLANE,256,0,stream>>>(x, A2, DFh, DFl, 0);
  k_chmean<<<288,256,0,stream>>>(A2, FNM);
  k_conv3<<<288,256,0,stream>>>(FNM, ec_w, E, P3);
  k_red576<<<1,256,0,stream>>>(P3, ST1);
  k_mask<<<8,256,0,stream>>>(E, ST1, bn1_g, bn1_b, nl_w, nl_b, MASK);
  // attention
  k_tr<<<dim3(288,8,8),dim3(32,8),0,stream>>>(x, XTH, XTL);
  for (int g=0; g<4; ++g){
    k_qkvm<<<576,256,0,stream>>>(XTH, XTL, QFh, QFl, qkv_b, QKV, g);
    k_attn<<<dim3(512,2),192,0,stream>>>(QKV, rpb, OH, OL, g);
  }
  k_projm<<<dim3(576,2),256,0,stream>>>(OH, OL, PFh, PFl, proj_b, PROJ);
  k_merge<<<dim3(768,4),256,0,stream>>>(PROJ, x, lpe_w, lpe_b, lpe_s, MASK, Y1);
  // frequency soft gate
  k_plane<<<NPLANE,256,0,stream>>>(Y1, G, DFh, DFl, 1);
  k_plane<<<NPLANE,256,0,stream>>>(G, XF, MFh, MFl, 2);
  // refine + BN2 + gelu
  k_wfrag_fr<<<256,256,0,stream>>>(fr_w, FFh, FFl);
  k_conv1x1m<<<1152,256,0,stream>>>(x, XF, FFh, FFl, Zb);
  k_bnstat<<<256,256,0,stream>>>(Zb, BN2);
  k_final<<<18432,256,0,stream>>>(Zb, BN2, bn2_g, bn2_b, outp);
}